// Round 7
// baseline (21.288 us; speedup 1.0000x reference)
//
#include <hip/hip_runtime.h>
#include <math.h>

#define H_DIM 512
#define N_DIM 32
#define L_LEN 1024

typedef float v2f __attribute__((ext_vector_type(2)));
__device__ __forceinline__ v2f splat2(float a) { return (v2f){a, a}; }

// DIF radix-2 inverse FFT, executed as radix-4 stage pairs.
// Butterfly twiddle W(s, r) = e^{+i*pi*r/s}. Thread t ends holding y[bitrev9(t)];
// a final LDS bit-reversal pass makes the global store coalesced.

__launch_bounds__(576, 5)
__global__ void ssk_nplr_kernel(const float* __restrict__ log_dt,
                                const float* __restrict__ inv_w_real,
                                const float* __restrict__ w_imag,
                                const float* __restrict__ B_ri,
                                const float* __restrict__ C_ri,
                                const float* __restrict__ P_ri,
                                float* __restrict__ out)
{
    __shared__ float2 Ksh[513];
    __shared__ float2 polD[N_DIM];   // {-2*Re(w*dt), |w*dt|^2}
    __shared__ float4 polA[N_DIM];   // a00,a01,a10,a11  (numer = a*z - b)
    __shared__ float4 polB[N_DIM];   // b00,b01,b10,b11
    __shared__ float  Sre[512], Sim[512];

    const int t = threadIdx.x;
    const int h = blockIdx.x;
    const float dt = expf(log_dt[h]);

    // ---------------- Phase A: per-h pole coefficients ----------------
    if (t < N_DIM) {
        const int n = t;
        float wr = -expf(inv_w_real[n]);   // S=1
        float wi = w_imag[n];
        float wdx = wr * dt, wdy = wi * dt;
        float Bx = B_ri[2*n],               By = B_ri[2*n+1];
        float Cx = C_ri[h*2*N_DIM + 2*n],   Cy = C_ri[h*2*N_DIM + 2*n+1];
        float Px = P_ri[2*n],               Py = P_ri[2*n+1];
        float v00x = Bx*Cx - By*Cy, v00y = Bx*Cy + By*Cx;   // B*C
        float v01x = Bx*Px + By*Py, v01y = By*Px - Bx*Py;   // B*conj(P)
        float v10x = Px*Cx - Py*Cy, v10y = Px*Cy + Py*Cx;   // P*C
        float v11x = Px*Px + Py*Py;                         // |P|^2
        polD[n] = make_float2(-2.0f*wdx, wdx*wdx + wdy*wdy);
        polA[n] = make_float4(2.0f*v00x, 2.0f*v01x, 2.0f*v10x, 2.0f*v11x);
        polB[n] = make_float4(2.0f*(v00x*wdx + v00y*wdy),
                              2.0f*(v01x*wdx + v01y*wdy),
                              2.0f*(v10x*wdx + v10y*wdy),
                              2.0f*(v11x*wdx));             // v11y = 0
    }

    // ---------------- Twiddle precompute (data-independent) ----------------
    // W(s, r) = e^{+i pi r/s}; hw sin/cos take revolutions -> rev = r/(2s).
    float w256c, w256s, w128c, w128s, w64c, w64s;
    float w32c, w32s, w16c, w16s, w8c, w8s, w4c, w4s;
    {
        float r256 = (float)(t & 255) * (1.0f/512.0f);
        float r128 = (float)(t & 127) * (1.0f/256.0f);
        float r64  = (float)(t &  63) * (1.0f/128.0f);
        float r32  = (float)(t &  31) * (1.0f/64.0f);
        float r16  = (float)(t &  15) * (1.0f/32.0f);
        float r8   = (float)(t &   7) * (1.0f/16.0f);
        float r4   = (float)(t &   3) * (1.0f/8.0f);
        w256s = __builtin_amdgcn_sinf(r256); w256c = __builtin_amdgcn_cosf(r256);
        w128s = __builtin_amdgcn_sinf(r128); w128c = __builtin_amdgcn_cosf(r128);
        w64s  = __builtin_amdgcn_sinf(r64);  w64c  = __builtin_amdgcn_cosf(r64);
        w32s  = __builtin_amdgcn_sinf(r32);  w32c  = __builtin_amdgcn_cosf(r32);
        w16s  = __builtin_amdgcn_sinf(r16);  w16c  = __builtin_amdgcn_cosf(r16);
        w8s   = __builtin_amdgcn_sinf(r8);   w8c   = __builtin_amdgcn_cosf(r8);
        w4s   = __builtin_amdgcn_sinf(r4);   w4c   = __builtin_amdgcn_cosf(r4);
    }

    // omega = e^{-2pi i j/1024}; j=512 emulates numpy's sinf(-pi_f32) (NaN guard).
    const int j = (t < 512) ? t : 512;
    float si, co;
    if (j == 512) {
        si = 8.7422777e-8f;
        co = -1.0f;
    } else {
        float rev = (float)j * (-0.0009765625f);           // -j/1024 revolutions
        si = __builtin_amdgcn_sinf(rev);
        co = __builtin_amdgcn_cosf(rev);
    }
    __syncthreads();

    // ---------------- Phase B: k_f[j] ----------------
    float px = 1.0f + co, py = si;                         // 1 + omega
    float pinv = 1.0f / (px*px + py*py);
    float ipx = px*pinv, ipy = -py*pinv;                   // 1/(1+omega)
    float mx = 1.0f - co, my = -si;                        // 1 - omega
    float zx = 2.0f*(mx*ipx - my*ipy);                     // z = 2(1-w)/(1+w)
    float zy = 2.0f*(mx*ipy + my*ipx);

    v2f Z  = { zx, zy };
    v2f Z2 = { zx*zx - zy*zy, 2.0f*zx*zy };

    v2f U0{0,0}, U1{0,0}, U2{0,0}, U3{0,0};
    v2f V0{0,0}, V1{0,0}, V2{0,0}, V3{0,0};
    #pragma unroll
    for (int n = 0; n < N_DIM; ++n) {
        float2 d  = polD[n];
        float4 A  = polA[n];
        float4 Bv = polB[n];
        v2f D = __builtin_elementwise_fma(splat2(d.x), Z, Z2);
        D.x += d.y;
        float s  = __builtin_amdgcn_rcpf(fmaf(D.x, D.x, D.y*D.y));
        v2f R = { D.x * s, -(D.y * s) };                   // 1/D
        U0 = __builtin_elementwise_fma(splat2(A.x),  R, U0);
        U1 = __builtin_elementwise_fma(splat2(A.y),  R, U1);
        U2 = __builtin_elementwise_fma(splat2(A.z),  R, U2);
        U3 = __builtin_elementwise_fma(splat2(A.w),  R, U3);
        V0 = __builtin_elementwise_fma(splat2(Bv.x), R, V0);
        V1 = __builtin_elementwise_fma(splat2(Bv.y), R, V1);
        V2 = __builtin_elementwise_fma(splat2(Bv.z), R, V2);
        V3 = __builtin_elementwise_fma(splat2(Bv.w), R, V3);
    }
    float r00x = dt*(zx*U0.x - zy*U0.y - V0.x), r00y = dt*(zx*U0.y + zy*U0.x - V0.y);
    float r01x = dt*(zx*U1.x - zy*U1.y - V1.x), r01y = dt*(zx*U1.y + zy*U1.x - V1.y);
    float r10x = dt*(zx*U2.x - zy*U2.y - V2.x), r10y = dt*(zx*U2.y + zy*U2.x - V2.y);
    float r11x = dt*(zx*U3.x - zy*U3.y - V3.x), r11y = dt*(zx*U3.y + zy*U3.x - V3.y);

    float dnx = 1.0f + r11x, dny = r11y;
    float dinv = 1.0f / (dnx*dnx + dny*dny);
    float idx_ = dnx*dinv, idy = -dny*dinv;
    float m01x = r01x*r10x - r01y*r10y;
    float m01y = r01x*r10y + r01y*r10x;
    float kfx = r00x - (m01x*idx_ - m01y*idy);
    float kfy = r00y - (m01x*idy + m01y*idx_);
    float fxv = 2.0f*(kfx*ipx - kfy*ipy);
    float fyv = 2.0f*(kfx*ipy + kfy*ipx);
    if (t <= 512) Ksh[j] = make_float2(fxv, fyv);
    __syncthreads();

    // ---------------- Phase C: irfft via packed complex IFFT(512) ----------------
    float xr = 0.0f, xi = 0.0f;
    if (t < 512) {
        // Hermitian -> complex packing fused with the s=256 butterfly.
        float2 Ka = Ksh[t];
        float2 Kb = Ksh[512 - t];
        const int tb = t ^ 256;
        float2 Kc = Ksh[tb];
        float2 Kd = Ksh[512 - tb];
        float Wx = co, Wy = -si;                   // e^{+2pi i t/1024}
        float hsx = 0.5f*(Ka.x + Kb.x), hsy = 0.5f*(Ka.y - Kb.y);
        float hdx = 0.5f*(Ka.x - Kb.x), hdy = 0.5f*(Ka.y + Kb.y);
        float Yax = hsx - Wy*hdx - Wx*hdy;
        float Yay = hsy - Wy*hdy + Wx*hdx;
        float Wbx = (t < 256) ? -Wy :  Wy;         // e^{+2pi i (t^256)/1024}
        float Wby = (t < 256) ?  Wx : -Wx;
        float hsx2 = 0.5f*(Kc.x + Kd.x), hsy2 = 0.5f*(Kc.y - Kd.y);
        float hdx2 = 0.5f*(Kc.x - Kd.x), hdy2 = 0.5f*(Kc.y + Kd.y);
        float Ybx = hsx2 - Wby*hdx2 - Wbx*hdy2;
        float Yby = hsy2 - Wby*hdy2 + Wbx*hdx2;
        if (t & 256) {
            float dr = Ybx - Yax, di = Yby - Yay;
            xr = dr*w256c - di*w256s; xi = dr*w256s + di*w256c;
        } else {
            xr = Yax + Ybx; xi = Yay + Yby;
        }
        Sre[t] = xr; Sim[t] = xi;
    }
    __syncthreads();

    if (t < 512) {
        // ---- radix-4 pair (128, 64) via one LDS round ----
        {
            float p1r = Sre[t ^ 128], p1i = Sim[t ^ 128];
            float p2r = Sre[t ^  64], p2i = Sim[t ^  64];
            float p3r = Sre[t ^ 192], p3i = Sim[t ^ 192];
            float Atr, Ati, Apr, Api;
            if (t & 128) {
                float dr = p1r - xr, di = p1i - xi;
                Atr = dr*w128c - di*w128s; Ati = dr*w128s + di*w128c;
                float er = p3r - p2r, ei = p3i - p2i;
                float wpr = (t & 64) ?  w128s : -w128s;   // -i*W1 : +i*W1
                float wpi = (t & 64) ? -w128c :  w128c;
                Apr = er*wpr - ei*wpi; Api = er*wpi + ei*wpr;
            } else {
                Atr = xr + p1r;  Ati = xi + p1i;
                Apr = p2r + p3r; Api = p2i + p3i;
            }
            if (t & 64) {
                float dr = Apr - Atr, di = Api - Ati;
                xr = dr*w64c - di*w64s; xi = dr*w64s + di*w64c;
            } else { xr = Atr + Apr; xi = Ati + Api; }
        }

        // ---- radix-4 pairs via 3 independent shfls each ----
        #define RADIX4S(S_, W1C, W1S, W2C, W2S) {                               \
            float p1r = __shfl_xor(xr, S_),        p1i = __shfl_xor(xi, S_);    \
            float p2r = __shfl_xor(xr, S_/2),      p2i = __shfl_xor(xi, S_/2);  \
            float p3r = __shfl_xor(xr, S_ + S_/2), p3i = __shfl_xor(xi, S_ + S_/2); \
            float Atr, Ati, Apr, Api;                                           \
            if (t & S_) {                                                       \
                float dr = p1r - xr, di = p1i - xi;                             \
                Atr = dr*W1C - di*W1S; Ati = dr*W1S + di*W1C;                   \
                float er = p3r - p2r, ei = p3i - p2i;                           \
                float wpr = (t & (S_/2)) ?  W1S : -W1S;                         \
                float wpi = (t & (S_/2)) ? -W1C :  W1C;                         \
                Apr = er*wpr - ei*wpi; Api = er*wpi + ei*wpr;                   \
            } else {                                                            \
                Atr = xr + p1r;  Ati = xi + p1i;                                \
                Apr = p2r + p3r; Api = p2i + p3i;                               \
            }                                                                   \
            if (t & (S_/2)) {                                                   \
                float dr = Apr - Atr, di = Api - Ati;                           \
                xr = dr*W2C - di*W2S; xi = dr*W2S + di*W2C;                     \
            } else { xr = Atr + Apr; xi = Ati + Api; }                          \
        }
        RADIX4S(32, w32c, w32s, w16c, w16s)
        RADIX4S(8,  w8c,  w8s,  w4c,  w4s)
        #undef RADIX4S

        // ---- final pair (2, 1): W in {1, i}, no trig ----
        {
            float p1r = __shfl_xor(xr, 2), p1i = __shfl_xor(xi, 2);
            float p2r = __shfl_xor(xr, 1), p2i = __shfl_xor(xi, 1);
            float p3r = __shfl_xor(xr, 3), p3i = __shfl_xor(xi, 3);
            float Atr, Ati, Apr, Api;
            if (t & 2) {
                float dr = p1r - xr, di = p1i - xi;
                float er = p3r - p2r, ei = p3i - p2i;
                if (t & 1) { Atr = -di; Ati =  dr;   // W1 = i
                             Apr =  er; Api =  ei; } // W1' = 1
                else       { Atr =  dr; Ati =  di;   // W1 = 1
                             Apr = -ei; Api =  er; } // W1' = i
            } else {
                Atr = xr + p1r;  Ati = xi + p1i;
                Apr = p2r + p3r; Api = p2i + p3i;
            }
            if (t & 1) { xr = Apr - Atr; xi = Api - Ati; }
            else       { xr = Atr + Apr; xi = Ati + Api; }
        }

        // ---- bit-reversal via (now dead) Ksh, for coalesced global stores ----
        unsigned m = __brev((unsigned)t) >> 23;
        Ksh[m] = make_float2(xr*(1.0f/512.0f), xi*(1.0f/512.0f));
    }
    __syncthreads();

    if (t < 512) {
        float2 o = Ksh[t];
        ((float2*)out)[h*512 + t] = o;     // coalesced: consecutive t -> consecutive 8B
    }
}

extern "C" void kernel_launch(void* const* d_in, const int* in_sizes, int n_in,
                              void* d_out, int out_size, void* d_ws, size_t ws_size,
                              hipStream_t stream) {
    const float* log_dt     = (const float*)d_in[0];
    const float* inv_w_real = (const float*)d_in[1];
    const float* w_imag     = (const float*)d_in[2];
    const float* B_ri       = (const float*)d_in[3];
    const float* C_ri       = (const float*)d_in[4];
    const float* P_ri       = (const float*)d_in[5];
    // d_in[6] = L (constant 1024, baked in)

    ssk_nplr_kernel<<<H_DIM, 576, 0, stream>>>(log_dt, inv_w_real, w_imag,
                                               B_ri, C_ri, P_ri, (float*)d_out);
}

// Round 8
// 19.353 us; speedup vs baseline: 1.1000x; 1.1000x over previous
//
#include <hip/hip_runtime.h>
#include <math.h>

#define H_DIM 512
#define N_DIM 32
#define L_LEN 1024
#define LF 513

typedef float v2f __attribute__((ext_vector_type(2)));
static __device__ __forceinline__ v2f splat2(float a) { return (v2f){a, a}; }

// ======================= Kernel 1: Cauchy stage =======================
// grid (H, 5); block 512 = 128 j-lanes x 4 pole-quarters (8 poles each).
// Tiles y=0..3 cover j in [128y, 128y+128); tile y=4 covers j=512 (jl==0).
__launch_bounds__(512, 8)
__global__ void k1_cauchy(const float* __restrict__ log_dt,
                          const float* __restrict__ inv_w_real,
                          const float* __restrict__ w_imag,
                          const float* __restrict__ B_ri,
                          const float* __restrict__ C_ri,
                          const float* __restrict__ P_ri,
                          float2* __restrict__ kf)      // [H][513]
{
    __shared__ float2 polD[N_DIM];         // {-2*Re(w*dt), |w*dt|^2}
    __shared__ float4 polA[N_DIM];         // a00,a01,a10,a11
    __shared__ float4 polB[N_DIM];         // b00,b01,b10,b11
    __shared__ float4 comb[4][4][128];     // [ph][chunk][jl] partial U/V sums

    const int t  = threadIdx.x;
    const int h  = blockIdx.x;
    const int jl = t & 127;
    const int ph = t >> 7;                 // pole quarter 0..3
    const int j  = blockIdx.y * 128 + jl;  // tile 4 -> only jl==0 (j=512) valid
    const bool active = (j <= 512);
    const float dt = expf(log_dt[h]);

    // ---- per-h pole coefficients (threads 0..31) ----
    if (t < N_DIM) {
        const int n = t;
        float wr = -expf(inv_w_real[n]);   // S=1
        float wi = w_imag[n];
        float wdx = wr * dt, wdy = wi * dt;
        float Bx = B_ri[2*n],               By = B_ri[2*n+1];
        float Cx = C_ri[h*2*N_DIM + 2*n],   Cy = C_ri[h*2*N_DIM + 2*n+1];
        float Px = P_ri[2*n],               Py = P_ri[2*n+1];
        float v00x = Bx*Cx - By*Cy, v00y = Bx*Cy + By*Cx;   // B*C
        float v01x = Bx*Px + By*Py, v01y = By*Px - Bx*Py;   // B*conj(P)
        float v10x = Px*Cx - Py*Cy, v10y = Px*Cy + Py*Cx;   // P*C
        float v11x = Px*Px + Py*Py;                         // |P|^2
        polD[n] = make_float2(-2.0f*wdx, wdx*wdx + wdy*wdy);
        polA[n] = make_float4(2.0f*v00x, 2.0f*v01x, 2.0f*v10x, 2.0f*v11x);
        polB[n] = make_float4(2.0f*(v00x*wdx + v00y*wdy),
                              2.0f*(v01x*wdx + v01y*wdy),
                              2.0f*(v10x*wdx + v10y*wdy),
                              2.0f*(v11x*wdx));             // v11y = 0
    }
    __syncthreads();

    // omega = e^{-2pi i j/1024}; j=512 emulates numpy's sinf(-pi_f32) (NaN guard).
    float si, co;
    if (j == 512) {
        si = 8.7422777e-8f;
        co = -1.0f;
    } else {
        float rev = (float)j * (-0.0009765625f);   // -j/1024 revolutions
        si = __builtin_amdgcn_sinf(rev);
        co = __builtin_amdgcn_cosf(rev);
    }

    float px = 1.0f + co, py = si;                 // 1 + omega
    float pinv = 1.0f / (px*px + py*py);
    float ipx = px*pinv, ipy = -py*pinv;           // 1/(1+omega)
    float mx = 1.0f - co, my = -si;                // 1 - omega
    float zx = 2.0f*(mx*ipx - my*ipy);             // z = 2(1-w)/(1+w)
    float zy = 2.0f*(mx*ipy + my*ipx);

    v2f Z  = { zx, zy };
    v2f Z2 = { zx*zx - zy*zy, 2.0f*zx*zy };

    v2f U0{0,0}, U1{0,0}, U2{0,0}, U3{0,0};
    v2f V0{0,0}, V1{0,0}, V2{0,0}, V3{0,0};
    const int n0 = ph * 8;
    #pragma unroll
    for (int k = 0; k < 8; ++k) {
        const int n = n0 + k;
        float2 d  = polD[n];
        float4 A  = polA[n];
        float4 Bv = polB[n];
        v2f D = __builtin_elementwise_fma(splat2(d.x), Z, Z2);
        D.x += d.y;
        float s  = __builtin_amdgcn_rcpf(fmaf(D.x, D.x, D.y*D.y));
        v2f R = { D.x * s, -(D.y * s) };           // 1/D
        U0 = __builtin_elementwise_fma(splat2(A.x),  R, U0);
        U1 = __builtin_elementwise_fma(splat2(A.y),  R, U1);
        U2 = __builtin_elementwise_fma(splat2(A.z),  R, U2);
        U3 = __builtin_elementwise_fma(splat2(A.w),  R, U3);
        V0 = __builtin_elementwise_fma(splat2(Bv.x), R, V0);
        V1 = __builtin_elementwise_fma(splat2(Bv.y), R, V1);
        V2 = __builtin_elementwise_fma(splat2(Bv.z), R, V2);
        V3 = __builtin_elementwise_fma(splat2(Bv.w), R, V3);
    }

    // ---- combine partials across the 4 pole-quarters ----
    comb[ph][0][jl] = make_float4(U0.x, U0.y, U1.x, U1.y);
    comb[ph][1][jl] = make_float4(U2.x, U2.y, U3.x, U3.y);
    comb[ph][2][jl] = make_float4(V0.x, V0.y, V1.x, V1.y);
    comb[ph][3][jl] = make_float4(V2.x, V2.y, V3.x, V3.y);
    __syncthreads();

    if (ph == 0 && active) {
        #pragma unroll
        for (int p = 1; p < 4; ++p) {
            float4 c0 = comb[p][0][jl];
            float4 c1 = comb[p][1][jl];
            float4 c2 = comb[p][2][jl];
            float4 c3 = comb[p][3][jl];
            U0.x += c0.x; U0.y += c0.y; U1.x += c0.z; U1.y += c0.w;
            U2.x += c1.x; U2.y += c1.y; U3.x += c1.z; U3.y += c1.w;
            V0.x += c2.x; V0.y += c2.y; V1.x += c2.z; V1.y += c2.w;
            V2.x += c3.x; V2.y += c3.y; V3.x += c3.z; V3.y += c3.w;
        }
        // r = dt * (z*U - V)
        float r00x = dt*(zx*U0.x - zy*U0.y - V0.x), r00y = dt*(zx*U0.y + zy*U0.x - V0.y);
        float r01x = dt*(zx*U1.x - zy*U1.y - V1.x), r01y = dt*(zx*U1.y + zy*U1.x - V1.y);
        float r10x = dt*(zx*U2.x - zy*U2.y - V2.x), r10y = dt*(zx*U2.y + zy*U2.x - V2.y);
        float r11x = dt*(zx*U3.x - zy*U3.y - V3.x), r11y = dt*(zx*U3.y + zy*U3.x - V3.y);

        // k_f = (r00 - r01*r10/(1+r11)) * 2/(1+omega)
        float dnx = 1.0f + r11x, dny = r11y;
        float dinv = 1.0f / (dnx*dnx + dny*dny);
        float idx_ = dnx*dinv, idy = -dny*dinv;
        float m01x = r01x*r10x - r01y*r10y;
        float m01y = r01x*r10y + r01y*r10x;
        float kfx = r00x - (m01x*idx_ - m01y*idy);
        float kfy = r00y - (m01x*idy + m01y*idx_);
        float fxv = 2.0f*(kfx*ipx - kfy*ipy);
        float fyv = 2.0f*(kfx*ipy + kfy*ipx);
        kf[h*LF + j] = make_float2(fxv, fyv);
    }
}

// ======================= Kernel 2: packed IFFT(512) =======================
// DIF radix-2 as radix-4 stage pairs; W(s,r) = e^{+i pi r/s}.
// Thread t ends holding y[bitrev9(t)]; y[m] packs (x[2m], x[2m+1]).
__launch_bounds__(512, 8)
__global__ void k2_ifft(const float2* __restrict__ kf,
                        float* __restrict__ out)
{
    __shared__ float2 Ksh[LF];
    __shared__ float  Sre[512], Sim[512];

    const int t = threadIdx.x;
    const int h = blockIdx.x;

    Ksh[t] = kf[h*LF + t];
    if (t == 0) Ksh[512] = kf[h*LF + 512];

    // twiddles (data-independent): W(s,r) = e^{+i pi r/s}, rev = r/(2s)
    float w256c, w256s, w128c, w128s, w64c, w64s;
    float w32c, w32s, w16c, w16s, w8c, w8s, w4c, w4s;
    {
        float r256 = (float)(t & 255) * (1.0f/512.0f);
        float r128 = (float)(t & 127) * (1.0f/256.0f);
        float r64  = (float)(t &  63) * (1.0f/128.0f);
        float r32  = (float)(t &  31) * (1.0f/64.0f);
        float r16  = (float)(t &  15) * (1.0f/32.0f);
        float r8   = (float)(t &   7) * (1.0f/16.0f);
        float r4   = (float)(t &   3) * (1.0f/8.0f);
        w256s = __builtin_amdgcn_sinf(r256); w256c = __builtin_amdgcn_cosf(r256);
        w128s = __builtin_amdgcn_sinf(r128); w128c = __builtin_amdgcn_cosf(r128);
        w64s  = __builtin_amdgcn_sinf(r64);  w64c  = __builtin_amdgcn_cosf(r64);
        w32s  = __builtin_amdgcn_sinf(r32);  w32c  = __builtin_amdgcn_cosf(r32);
        w16s  = __builtin_amdgcn_sinf(r16);  w16c  = __builtin_amdgcn_cosf(r16);
        w8s   = __builtin_amdgcn_sinf(r8);   w8c   = __builtin_amdgcn_cosf(r8);
        w4s   = __builtin_amdgcn_sinf(r4);   w4c   = __builtin_amdgcn_cosf(r4);
    }
    float rev = (float)t * (-0.0009765625f);       // -t/1024, t < 512: no NaN case
    float si = __builtin_amdgcn_sinf(rev);
    float co = __builtin_amdgcn_cosf(rev);
    __syncthreads();

    // Hermitian -> complex packing fused with the s=256 butterfly.
    float xr, xi;
    {
        float2 Ka = Ksh[t];
        float2 Kb = Ksh[512 - t];
        const int tb = t ^ 256;
        float2 Kc = Ksh[tb];
        float2 Kd = Ksh[512 - tb];
        float Wx = co, Wy = -si;                   // e^{+2pi i t/1024}
        float hsx = 0.5f*(Ka.x + Kb.x), hsy = 0.5f*(Ka.y - Kb.y);
        float hdx = 0.5f*(Ka.x - Kb.x), hdy = 0.5f*(Ka.y + Kb.y);
        float Yax = hsx - Wy*hdx - Wx*hdy;
        float Yay = hsy - Wy*hdy + Wx*hdx;
        float Wbx = (t < 256) ? -Wy :  Wy;         // e^{+2pi i (t^256)/1024}
        float Wby = (t < 256) ?  Wx : -Wx;
        float hsx2 = 0.5f*(Kc.x + Kd.x), hsy2 = 0.5f*(Kc.y - Kd.y);
        float hdx2 = 0.5f*(Kc.x - Kd.x), hdy2 = 0.5f*(Kc.y + Kd.y);
        float Ybx = hsx2 - Wby*hdx2 - Wbx*hdy2;
        float Yby = hsy2 - Wby*hdy2 + Wbx*hdx2;
        if (t & 256) {
            float dr = Ybx - Yax, di = Yby - Yay;
            xr = dr*w256c - di*w256s; xi = dr*w256s + di*w256c;
        } else {
            xr = Yax + Ybx; xi = Yay + Yby;
        }
        Sre[t] = xr; Sim[t] = xi;
    }
    __syncthreads();

    // ---- radix-4 pair (128, 64) via one LDS round ----
    {
        float p1r = Sre[t ^ 128], p1i = Sim[t ^ 128];
        float p2r = Sre[t ^  64], p2i = Sim[t ^  64];
        float p3r = Sre[t ^ 192], p3i = Sim[t ^ 192];
        float Atr, Ati, Apr, Api;
        if (t & 128) {
            float dr = p1r - xr, di = p1i - xi;
            Atr = dr*w128c - di*w128s; Ati = dr*w128s + di*w128c;
            float er = p3r - p2r, ei = p3i - p2i;
            float wpr = (t & 64) ?  w128s : -w128s;   // -i*W1 : +i*W1
            float wpi = (t & 64) ? -w128c :  w128c;
            Apr = er*wpr - ei*wpi; Api = er*wpi + ei*wpr;
        } else {
            Atr = xr + p1r;  Ati = xi + p1i;
            Apr = p2r + p3r; Api = p2i + p3i;
        }
        if (t & 64) {
            float dr = Apr - Atr, di = Api - Ati;
            xr = dr*w64c - di*w64s; xi = dr*w64s + di*w64c;
        } else { xr = Atr + Apr; xi = Ati + Api; }
    }

    // ---- radix-4 pairs via 3 independent shfls each ----
    #define RADIX4S(S_, W1C, W1S, W2C, W2S) {                               \
        float p1r = __shfl_xor(xr, S_),        p1i = __shfl_xor(xi, S_);    \
        float p2r = __shfl_xor(xr, S_/2),      p2i = __shfl_xor(xi, S_/2);  \
        float p3r = __shfl_xor(xr, S_ + S_/2), p3i = __shfl_xor(xi, S_ + S_/2); \
        float Atr, Ati, Apr, Api;                                           \
        if (t & S_) {                                                       \
            float dr = p1r - xr, di = p1i - xi;                             \
            Atr = dr*W1C - di*W1S; Ati = dr*W1S + di*W1C;                   \
            float er = p3r - p2r, ei = p3i - p2i;                           \
            float wpr = (t & (S_/2)) ?  W1S : -W1S;                         \
            float wpi = (t & (S_/2)) ? -W1C :  W1C;                         \
            Apr = er*wpr - ei*wpi; Api = er*wpi + ei*wpr;                   \
        } else {                                                            \
            Atr = xr + p1r;  Ati = xi + p1i;                                \
            Apr = p2r + p3r; Api = p2i + p3i;                               \
        }                                                                   \
        if (t & (S_/2)) {                                                   \
            float dr = Apr - Atr, di = Api - Ati;                           \
            xr = dr*W2C - di*W2S; xi = dr*W2S + di*W2C;                     \
        } else { xr = Atr + Apr; xi = Ati + Api; }                          \
    }
    RADIX4S(32, w32c, w32s, w16c, w16s)
    RADIX4S(8,  w8c,  w8s,  w4c,  w4s)
    #undef RADIX4S

    // ---- final pair (2, 1): W in {1, i}, no trig ----
    {
        float p1r = __shfl_xor(xr, 2), p1i = __shfl_xor(xi, 2);
        float p2r = __shfl_xor(xr, 1), p2i = __shfl_xor(xi, 1);
        float p3r = __shfl_xor(xr, 3), p3i = __shfl_xor(xi, 3);
        float Atr, Ati, Apr, Api;
        if (t & 2) {
            float dr = p1r - xr, di = p1i - xi;
            float er = p3r - p2r, ei = p3i - p2i;
            if (t & 1) { Atr = -di; Ati =  dr;   // W1 = i
                         Apr =  er; Api =  ei; } // W1' = 1
            else       { Atr =  dr; Ati =  di;   // W1 = 1
                         Apr = -ei; Api =  er; } // W1' = i
        } else {
            Atr = xr + p1r;  Ati = xi + p1i;
            Apr = p2r + p3r; Api = p2i + p3i;
        }
        if (t & 1) { xr = Apr - Atr; xi = Api - Ati; }
        else       { xr = Atr + Apr; xi = Ati + Api; }
    }

    unsigned m = __brev((unsigned)t) >> 23;
    ((float2*)out)[h*512 + m] = make_float2(xr*(1.0f/512.0f), xi*(1.0f/512.0f));
}

extern "C" void kernel_launch(void* const* d_in, const int* in_sizes, int n_in,
                              void* d_out, int out_size, void* d_ws, size_t ws_size,
                              hipStream_t stream) {
    const float* log_dt     = (const float*)d_in[0];
    const float* inv_w_real = (const float*)d_in[1];
    const float* w_imag     = (const float*)d_in[2];
    const float* B_ri       = (const float*)d_in[3];
    const float* C_ri       = (const float*)d_in[4];
    const float* P_ri       = (const float*)d_in[5];
    // d_in[6] = L (constant 1024, baked in)

    float2* kf = (float2*)d_ws;            // 512*513*8B = 2.1 MB << ws_size

    dim3 g1(H_DIM, 5);
    k1_cauchy<<<g1, 512, 0, stream>>>(log_dt, inv_w_real, w_imag,
                                      B_ri, C_ri, P_ri, kf);
    k2_ifft<<<H_DIM, 512, 0, stream>>>(kf, (float*)d_out);
}

// Round 9
// 16.428 us; speedup vs baseline: 1.2958x; 1.1780x over previous
//
#include <hip/hip_runtime.h>
#include <math.h>

#define H_DIM 512
#define N_DIM 32

typedef float v2f __attribute__((ext_vector_type(2)));
static __device__ __forceinline__ v2f splat2(float a) { return (v2f){a, a}; }

// Woodbury epilogue: r = dt*(z*U - V); k_f = (r00 - r01*r10/(1+r11)) * 2/(1+omega)
static __device__ __forceinline__ float2 woodbury(
    v2f U0, v2f U1, v2f U2, v2f U3,
    v2f V0, v2f V1, v2f V2, v2f V3,
    float zx, float zy, float dt, float ipx, float ipy)
{
    float r00x = dt*(zx*U0.x - zy*U0.y - V0.x), r00y = dt*(zx*U0.y + zy*U0.x - V0.y);
    float r01x = dt*(zx*U1.x - zy*U1.y - V1.x), r01y = dt*(zx*U1.y + zy*U1.x - V1.y);
    float r10x = dt*(zx*U2.x - zy*U2.y - V2.x), r10y = dt*(zx*U2.y + zy*U2.x - V2.y);
    float r11x = dt*(zx*U3.x - zy*U3.y - V3.x), r11y = dt*(zx*U3.y + zy*U3.x - V3.y);
    float dnx = 1.0f + r11x, dny = r11y;
    float dinv = 1.0f / (dnx*dnx + dny*dny);
    float idx_ = dnx*dinv, idy = -dny*dinv;
    float m01x = r01x*r10x - r01y*r10y;
    float m01y = r01x*r10y + r01y*r10x;
    float kfx = r00x - (m01x*idx_ - m01y*idy);
    float kfy = r00y - (m01x*idy + m01y*idx_);
    return make_float2(2.0f*(kfx*ipx - kfy*ipy),
                       2.0f*(kfx*ipy + kfy*ipx));
}

// DIF radix-2 inverse FFT as radix-4 stage pairs; W(s,r) = e^{+i pi r/s}.
// Thread t ends holding y[bitrev9(t)]; y[m] packs (x[2m], x[2m+1]).
__launch_bounds__(512, 4)
__global__ void ssk_nplr_kernel(const float* __restrict__ log_dt,
                                const float* __restrict__ inv_w_real,
                                const float* __restrict__ w_imag,
                                const float* __restrict__ B_ri,
                                const float* __restrict__ C_ri,
                                const float* __restrict__ P_ri,
                                float* __restrict__ out)
{
    __shared__ float2 Ksh[513];
    __shared__ float2 polD[N_DIM];   // {-2*Re(w*dt), |w*dt|^2}
    __shared__ float4 polA[N_DIM];   // a00,a01,a10,a11  (numer = a*z - b, a,b REAL)
    __shared__ float4 polB[N_DIM];   // b00,b01,b10,b11
    __shared__ float  Sre[512], Sim[512];

    const int t = threadIdx.x;
    const int h = blockIdx.x;
    const float dt = expf(log_dt[h]);

    // ---------------- Phase A: per-h pole coefficients ----------------
    if (t < N_DIM) {
        const int n = t;
        float wr = -expf(inv_w_real[n]);   // S=1
        float wi = w_imag[n];
        float wdx = wr * dt, wdy = wi * dt;
        float Bx = B_ri[2*n],               By = B_ri[2*n+1];
        float Cx = C_ri[h*2*N_DIM + 2*n],   Cy = C_ri[h*2*N_DIM + 2*n+1];
        float Px = P_ri[2*n],               Py = P_ri[2*n+1];
        float v00x = Bx*Cx - By*Cy, v00y = Bx*Cy + By*Cx;   // B*C
        float v01x = Bx*Px + By*Py, v01y = By*Px - Bx*Py;   // B*conj(P)
        float v10x = Px*Cx - Py*Cy, v10y = Px*Cy + Py*Cx;   // P*C
        float v11x = Px*Px + Py*Py;                         // |P|^2
        polD[n] = make_float2(-2.0f*wdx, wdx*wdx + wdy*wdy);
        polA[n] = make_float4(2.0f*v00x, 2.0f*v01x, 2.0f*v10x, 2.0f*v11x);
        polB[n] = make_float4(2.0f*(v00x*wdx + v00y*wdy),
                              2.0f*(v01x*wdx + v01y*wdy),
                              2.0f*(v10x*wdx + v10y*wdy),
                              2.0f*(v11x*wdx));             // v11y = 0
    }

    // ---------------- FFT twiddles + packing twiddle (data-independent) ----------------
    float w256c, w256s, w128c, w128s, w64c, w64s;
    float w32c, w32s, w16c, w16s, w8c, w8s, w4c, w4s;
    {
        float r256 = (float)(t & 255) * (1.0f/512.0f);
        float r128 = (float)(t & 127) * (1.0f/256.0f);
        float r64  = (float)(t &  63) * (1.0f/128.0f);
        float r32  = (float)(t &  31) * (1.0f/64.0f);
        float r16  = (float)(t &  15) * (1.0f/32.0f);
        float r8   = (float)(t &   7) * (1.0f/16.0f);
        float r4   = (float)(t &   3) * (1.0f/8.0f);
        w256s = __builtin_amdgcn_sinf(r256); w256c = __builtin_amdgcn_cosf(r256);
        w128s = __builtin_amdgcn_sinf(r128); w128c = __builtin_amdgcn_cosf(r128);
        w64s  = __builtin_amdgcn_sinf(r64);  w64c  = __builtin_amdgcn_cosf(r64);
        w32s  = __builtin_amdgcn_sinf(r32);  w32c  = __builtin_amdgcn_cosf(r32);
        w16s  = __builtin_amdgcn_sinf(r16);  w16c  = __builtin_amdgcn_cosf(r16);
        w8s   = __builtin_amdgcn_sinf(r8);   w8c   = __builtin_amdgcn_cosf(r8);
        w4s   = __builtin_amdgcn_sinf(r4);   w4c   = __builtin_amdgcn_cosf(r4);
    }
    // packing twiddle e^{+2pi i t/1024}
    float Wx, Wy;
    {
        float pr = (float)t * 0.0009765625f;       // +t/1024 revolutions
        Wy = __builtin_amdgcn_sinf(pr);
        Wx = __builtin_amdgcn_cosf(pr);
    }
    __syncthreads();

    // ---------------- Phase B: threads 0..256, TWO j's per thread ----------------
    // j1 = t in [0,256], j2 = t+256 in [256,512]. Each pole's LDS data is
    // loaded ONCE and used for both j's (halves LDS-pipe traffic).
    if (t < 257) {
        const int j1 = t, j2 = t + 256;
        float s1, c1, s2, c2;
        {
            float rev1 = (float)j1 * (-0.0009765625f);
            s1 = __builtin_amdgcn_sinf(rev1);
            c1 = __builtin_amdgcn_cosf(rev1);
        }
        if (j2 == 512) {   // numpy computes sinf(-pi_f32) ~= +8.7422777e-8: finite-huge z
            s2 = 8.7422777e-8f;
            c2 = -1.0f;
        } else {
            float rev2 = (float)j2 * (-0.0009765625f);
            s2 = __builtin_amdgcn_sinf(rev2);
            c2 = __builtin_amdgcn_cosf(rev2);
        }

        // z = 2(1-omega)/(1+omega) for both j's
        float pxa = 1.0f + c1, pya = s1;
        float pia = 1.0f / (pxa*pxa + pya*pya);
        float ipxa = pxa*pia, ipya = -pya*pia;
        float mxa = 1.0f - c1, mya = -s1;
        float zxa = 2.0f*(mxa*ipxa - mya*ipya);
        float zya = 2.0f*(mxa*ipya + mya*ipxa);

        float pxb = 1.0f + c2, pyb = s2;
        float pib = 1.0f / (pxb*pxb + pyb*pyb);
        float ipxb = pxb*pib, ipyb = -pyb*pib;
        float mxb = 1.0f - c2, myb = -s2;
        float zxb = 2.0f*(mxb*ipxb - myb*ipyb);
        float zyb = 2.0f*(mxb*ipyb + myb*ipxb);

        v2f Za  = { zxa, zya };
        v2f Z2a = { zxa*zxa - zya*zya, 2.0f*zxa*zya };
        v2f Zb  = { zxb, zyb };
        v2f Z2b = { zxb*zxb - zyb*zyb, 2.0f*zxb*zyb };

        v2f Ua0{0,0}, Ua1{0,0}, Ua2{0,0}, Ua3{0,0};
        v2f Va0{0,0}, Va1{0,0}, Va2{0,0}, Va3{0,0};
        v2f Ub0{0,0}, Ub1{0,0}, Ub2{0,0}, Ub3{0,0};
        v2f Vb0{0,0}, Vb1{0,0}, Vb2{0,0}, Vb3{0,0};

        #pragma unroll 4
        for (int n = 0; n < N_DIM; ++n) {
            float2 d  = polD[n];
            float4 A  = polA[n];
            float4 Bv = polB[n];
            // shared pole-pair denominator D = z^2 - 2Re(wdt) z + |wdt|^2
            v2f Da = __builtin_elementwise_fma(splat2(d.x), Za, Z2a);
            Da.x += d.y;
            v2f Db = __builtin_elementwise_fma(splat2(d.x), Zb, Z2b);
            Db.x += d.y;
            float sa = __builtin_amdgcn_rcpf(fmaf(Da.x, Da.x, Da.y*Da.y));
            float sb = __builtin_amdgcn_rcpf(fmaf(Db.x, Db.x, Db.y*Db.y));
            v2f Ra = { Da.x * sa, -(Da.y * sa) };
            v2f Rb = { Db.x * sb, -(Db.y * sb) };
            Ua0 = __builtin_elementwise_fma(splat2(A.x),  Ra, Ua0);
            Ua1 = __builtin_elementwise_fma(splat2(A.y),  Ra, Ua1);
            Ua2 = __builtin_elementwise_fma(splat2(A.z),  Ra, Ua2);
            Ua3 = __builtin_elementwise_fma(splat2(A.w),  Ra, Ua3);
            Va0 = __builtin_elementwise_fma(splat2(Bv.x), Ra, Va0);
            Va1 = __builtin_elementwise_fma(splat2(Bv.y), Ra, Va1);
            Va2 = __builtin_elementwise_fma(splat2(Bv.z), Ra, Va2);
            Va3 = __builtin_elementwise_fma(splat2(Bv.w), Ra, Va3);
            Ub0 = __builtin_elementwise_fma(splat2(A.x),  Rb, Ub0);
            Ub1 = __builtin_elementwise_fma(splat2(A.y),  Rb, Ub1);
            Ub2 = __builtin_elementwise_fma(splat2(A.z),  Rb, Ub2);
            Ub3 = __builtin_elementwise_fma(splat2(A.w),  Rb, Ub3);
            Vb0 = __builtin_elementwise_fma(splat2(Bv.x), Rb, Vb0);
            Vb1 = __builtin_elementwise_fma(splat2(Bv.y), Rb, Vb1);
            Vb2 = __builtin_elementwise_fma(splat2(Bv.z), Rb, Vb2);
            Vb3 = __builtin_elementwise_fma(splat2(Bv.w), Rb, Vb3);
        }

        Ksh[j1] = woodbury(Ua0, Ua1, Ua2, Ua3, Va0, Va1, Va2, Va3,
                           zxa, zya, dt, ipxa, ipya);
        Ksh[j2] = woodbury(Ub0, Ub1, Ub2, Ub3, Vb0, Vb1, Vb2, Vb3,
                           zxb, zyb, dt, ipxb, ipyb);
    }
    __syncthreads();

    // ---------------- Phase C: irfft via packed complex IFFT(512) ----------------
    float xr, xi;
    {
        // Hermitian -> complex packing fused with the s=256 butterfly.
        float2 Ka = Ksh[t];
        float2 Kb = Ksh[512 - t];
        const int tb = t ^ 256;
        float2 Kc = Ksh[tb];
        float2 Kd = Ksh[512 - tb];
        float hsx = 0.5f*(Ka.x + Kb.x), hsy = 0.5f*(Ka.y - Kb.y);
        float hdx = 0.5f*(Ka.x - Kb.x), hdy = 0.5f*(Ka.y + Kb.y);
        float Yax = hsx - Wy*hdx - Wx*hdy;
        float Yay = hsy - Wy*hdy + Wx*hdx;
        float Wbx = (t < 256) ? -Wy :  Wy;         // e^{+2pi i (t^256)/1024}
        float Wby = (t < 256) ?  Wx : -Wx;
        float hsx2 = 0.5f*(Kc.x + Kd.x), hsy2 = 0.5f*(Kc.y - Kd.y);
        float hdx2 = 0.5f*(Kc.x - Kd.x), hdy2 = 0.5f*(Kc.y + Kd.y);
        float Ybx = hsx2 - Wby*hdx2 - Wbx*hdy2;
        float Yby = hsy2 - Wby*hdy2 + Wbx*hdx2;
        if (t & 256) {
            float dr = Ybx - Yax, di = Yby - Yay;
            xr = dr*w256c - di*w256s; xi = dr*w256s + di*w256c;
        } else {
            xr = Yax + Ybx; xi = Yay + Yby;
        }
        Sre[t] = xr; Sim[t] = xi;
    }
    __syncthreads();

    // ---- radix-4 pair (128, 64) via one LDS round ----
    {
        float p1r = Sre[t ^ 128], p1i = Sim[t ^ 128];
        float p2r = Sre[t ^  64], p2i = Sim[t ^  64];
        float p3r = Sre[t ^ 192], p3i = Sim[t ^ 192];
        float Atr, Ati, Apr, Api;
        if (t & 128) {
            float dr = p1r - xr, di = p1i - xi;
            Atr = dr*w128c - di*w128s; Ati = dr*w128s + di*w128c;
            float er = p3r - p2r, ei = p3i - p2i;
            float wpr = (t & 64) ?  w128s : -w128s;   // -i*W1 : +i*W1
            float wpi = (t & 64) ? -w128c :  w128c;
            Apr = er*wpr - ei*wpi; Api = er*wpi + ei*wpr;
        } else {
            Atr = xr + p1r;  Ati = xi + p1i;
            Apr = p2r + p3r; Api = p2i + p3i;
        }
        if (t & 64) {
            float dr = Apr - Atr, di = Api - Ati;
            xr = dr*w64c - di*w64s; xi = dr*w64s + di*w64c;
        } else { xr = Atr + Apr; xi = Ati + Api; }
    }

    // ---- radix-4 pairs via 3 independent shfls each ----
    #define RADIX4S(S_, W1C, W1S, W2C, W2S) {                               \
        float p1r = __shfl_xor(xr, S_),        p1i = __shfl_xor(xi, S_);    \
        float p2r = __shfl_xor(xr, S_/2),      p2i = __shfl_xor(xi, S_/2);  \
        float p3r = __shfl_xor(xr, S_ + S_/2), p3i = __shfl_xor(xi, S_ + S_/2); \
        float Atr, Ati, Apr, Api;                                           \
        if (t & S_) {                                                       \
            float dr = p1r - xr, di = p1i - xi;                             \
            Atr = dr*W1C - di*W1S; Ati = dr*W1S + di*W1C;                   \
            float er = p3r - p2r, ei = p3i - p2i;                           \
            float wpr = (t & (S_/2)) ?  W1S : -W1S;                         \
            float wpi = (t & (S_/2)) ? -W1C :  W1C;                         \
            Apr = er*wpr - ei*wpi; Api = er*wpi + ei*wpr;                   \
        } else {                                                            \
            Atr = xr + p1r;  Ati = xi + p1i;                                \
            Apr = p2r + p3r; Api = p2i + p3i;                               \
        }                                                                   \
        if (t & (S_/2)) {                                                   \
            float dr = Apr - Atr, di = Api - Ati;                           \
            xr = dr*W2C - di*W2S; xi = dr*W2S + di*W2C;                     \
        } else { xr = Atr + Apr; xi = Ati + Api; }                          \
    }
    RADIX4S(32, w32c, w32s, w16c, w16s)
    RADIX4S(8,  w8c,  w8s,  w4c,  w4s)
    #undef RADIX4S

    // ---- final pair (2, 1): W in {1, i}, no trig ----
    {
        float p1r = __shfl_xor(xr, 2), p1i = __shfl_xor(xi, 2);
        float p2r = __shfl_xor(xr, 1), p2i = __shfl_xor(xi, 1);
        float p3r = __shfl_xor(xr, 3), p3i = __shfl_xor(xi, 3);
        float Atr, Ati, Apr, Api;
        if (t & 2) {
            float dr = p1r - xr, di = p1i - xi;
            float er = p3r - p2r, ei = p3i - p2i;
            if (t & 1) { Atr = -di; Ati =  dr;   // W1 = i
                         Apr =  er; Api =  ei; } // W1' = 1
            else       { Atr =  dr; Ati =  di;   // W1 = 1
                         Apr = -ei; Api =  er; } // W1' = i
        } else {
            Atr = xr + p1r;  Ati = xi + p1i;
            Apr = p2r + p3r; Api = p2i + p3i;
        }
        if (t & 1) { xr = Apr - Atr; xi = Api - Ati; }
        else       { xr = Atr + Apr; xi = Ati + Api; }
    }

    // thread t holds y[bitrev9(t)]; y[m] packs (x[2m], x[2m+1])
    unsigned m = __brev((unsigned)t) >> 23;
    ((float2*)out)[h*512 + m] = make_float2(xr*(1.0f/512.0f), xi*(1.0f/512.0f));
}

extern "C" void kernel_launch(void* const* d_in, const int* in_sizes, int n_in,
                              void* d_out, int out_size, void* d_ws, size_t ws_size,
                              hipStream_t stream) {
    const float* log_dt     = (const float*)d_in[0];
    const float* inv_w_real = (const float*)d_in[1];
    const float* w_imag     = (const float*)d_in[2];
    const float* B_ri       = (const float*)d_in[3];
    const float* C_ri       = (const float*)d_in[4];
    const float* P_ri       = (const float*)d_in[5];
    // d_in[6] = L (constant 1024, baked in)

    ssk_nplr_kernel<<<H_DIM, 512, 0, stream>>>(log_dt, inv_w_real, w_imag,
                                               B_ri, C_ri, P_ri, (float*)d_out);
}

// Round 10
// 15.524 us; speedup vs baseline: 1.3713x; 1.0582x over previous
//
#include <hip/hip_runtime.h>
#include <math.h>

#define H_DIM 512
#define N_DIM 32
#define L_LEN 1024

typedef float v2f __attribute__((ext_vector_type(2)));
__device__ __forceinline__ v2f splat2(float a) { return (v2f){a, a}; }

// DIF radix-2 inverse FFT; butterfly twiddle W(s, r) = e^{+pi*i*r/s}.
// Stages: s=256 fused with Hermitian packing, 128/64 via LDS, 32..1 via shfl.
// Thread t ends holding y[bitrev9(t)].

__launch_bounds__(576, 7)
__global__ void ssk_nplr_kernel(const float* __restrict__ log_dt,
                                const float* __restrict__ inv_w_real,
                                const float* __restrict__ w_imag,
                                const float* __restrict__ B_ri,
                                const float* __restrict__ C_ri,
                                const float* __restrict__ P_ri,
                                float* __restrict__ out)
{
    __shared__ float2 Ksh[513];
    __shared__ float2 polD[N_DIM];   // {-2*Re(w*dt), |w*dt|^2}
    __shared__ float4 polA[N_DIM];   // a00,a01,a10,a11  (numer = a*z - b)
    __shared__ float4 polB[N_DIM];   // b00,b01,b10,b11
    __shared__ float  Sre[512], Sim[512];
    __shared__ float  Tre[512], Tim[512];

    const int t = threadIdx.x;
    const int h = blockIdx.x;
    const float dt = expf(log_dt[h]);

    // ---------------- Phase A: per-h pole coefficients ----------------
    if (t < N_DIM) {
        const int n = t;
        float wr = -expf(inv_w_real[n]);   // S=1
        float wi = w_imag[n];
        float wdx = wr * dt, wdy = wi * dt;
        float Bx = B_ri[2*n],               By = B_ri[2*n+1];
        float Cx = C_ri[h*2*N_DIM + 2*n],   Cy = C_ri[h*2*N_DIM + 2*n+1];
        float Px = P_ri[2*n],               Py = P_ri[2*n+1];
        float v00x = Bx*Cx - By*Cy, v00y = Bx*Cy + By*Cx;   // B*C
        float v01x = Bx*Px + By*Py, v01y = By*Px - Bx*Py;   // B*conj(P)
        float v10x = Px*Cx - Py*Cy, v10y = Px*Cy + Py*Cx;   // P*C
        float v11x = Px*Px + Py*Py;                         // |P|^2
        polD[n] = make_float2(-2.0f*wdx, wdx*wdx + wdy*wdy);
        polA[n] = make_float4(2.0f*v00x, 2.0f*v01x, 2.0f*v10x, 2.0f*v11x);
        polB[n] = make_float4(2.0f*(v00x*wdx + v00y*wdy),
                              2.0f*(v01x*wdx + v01y*wdy),
                              2.0f*(v10x*wdx + v10y*wdy),
                              2.0f*(v11x*wdx));             // v11y = 0
    }
    __syncthreads();

    // ---------------- Phase B: k_f[j] ----------------
    // threads 0..511 -> j = t ; wave 8 redundantly computes j = 512.
    const int j = (t < 512) ? t : 512;
    // omega = e^{-2pi i j/1024}; hw sin/cos take REVOLUTIONS (exact dyadic input).
    // j=512: rev=-0.5 exactly -> hw gives (si=0, co=-1) -> 1/(1+omega) = inf/NaN.
    // The numpy reference computes sinf(-pi_f32) ~= +8.7422777e-8 (pi_f32 != pi),
    // giving a huge-but-finite z whose magnitude cancels to first order in k_f.
    // Emulate that path with the libm f32 constants (wave-uniform branch).
    float si, co;
    if (j == 512) {
        si = 8.7422777e-8f;
        co = -1.0f;
    } else {
        float rev = (float)j * (-0.0009765625f);           // -j/1024 revolutions
        si = __builtin_amdgcn_sinf(rev);
        co = __builtin_amdgcn_cosf(rev);
    }

    float px = 1.0f + co, py = si;                         // 1 + omega
    float pinv = 1.0f / (px*px + py*py);
    float ipx = px*pinv, ipy = -py*pinv;                   // 1/(1+omega)
    float mx = 1.0f - co, my = -si;                        // 1 - omega
    float zx = 2.0f*(mx*ipx - my*ipy);                     // z = 2(1-w)/(1+w)
    float zy = 2.0f*(mx*ipy + my*ipx);

    v2f Z  = { zx, zy };
    v2f Z2 = { zx*zx - zy*zy, 2.0f*zx*zy };

    v2f U0{0,0}, U1{0,0}, U2{0,0}, U3{0,0};
    v2f V0{0,0}, V1{0,0}, V2{0,0}, V3{0,0};
    #pragma unroll 4
    for (int n = 0; n < N_DIM; ++n) {
        float2 d  = polD[n];
        float4 A  = polA[n];
        float4 Bv = polB[n];
        // shared pole-pair denominator D = z^2 - 2Re(wdt) z + |wdt|^2
        v2f D = __builtin_elementwise_fma(splat2(d.x), Z, Z2);
        D.x += d.y;
        float s  = __builtin_amdgcn_rcpf(fmaf(D.x, D.x, D.y*D.y));
        v2f R = { D.x * s, -(D.y * s) };                   // 1/D
        // S_v = z*U_v - V_v with U += a/D, V += b/D   (packed fma pairs)
        U0 = __builtin_elementwise_fma(splat2(A.x),  R, U0);
        U1 = __builtin_elementwise_fma(splat2(A.y),  R, U1);
        U2 = __builtin_elementwise_fma(splat2(A.z),  R, U2);
        U3 = __builtin_elementwise_fma(splat2(A.w),  R, U3);
        V0 = __builtin_elementwise_fma(splat2(Bv.x), R, V0);
        V1 = __builtin_elementwise_fma(splat2(Bv.y), R, V1);
        V2 = __builtin_elementwise_fma(splat2(Bv.z), R, V2);
        V3 = __builtin_elementwise_fma(splat2(Bv.w), R, V3);
    }
    // r = dt * (z*U - V)
    float r00x = dt*(zx*U0.x - zy*U0.y - V0.x), r00y = dt*(zx*U0.y + zy*U0.x - V0.y);
    float r01x = dt*(zx*U1.x - zy*U1.y - V1.x), r01y = dt*(zx*U1.y + zy*U1.x - V1.y);
    float r10x = dt*(zx*U2.x - zy*U2.y - V2.x), r10y = dt*(zx*U2.y + zy*U2.x - V2.y);
    float r11x = dt*(zx*U3.x - zy*U3.y - V3.x), r11y = dt*(zx*U3.y + zy*U3.x - V3.y);

    // k_f = (r00 - r01*r10/(1+r11)) * 2/(1+omega)
    float dnx = 1.0f + r11x, dny = r11y;
    float dinv = 1.0f / (dnx*dnx + dny*dny);
    float idx_ = dnx*dinv, idy = -dny*dinv;
    float m01x = r01x*r10x - r01y*r10y;
    float m01y = r01x*r10y + r01y*r10x;
    float kfx = r00x - (m01x*idx_ - m01y*idy);
    float kfy = r00y - (m01x*idy + m01y*idx_);
    float fxv = 2.0f*(kfx*ipx - kfy*ipy);
    float fyv = 2.0f*(kfx*ipy + kfy*ipx);
    if (t <= 512) Ksh[j] = make_float2(fxv, fyv);
    __syncthreads();

    // ---------------- Phase C: irfft via packed complex IFFT(512), DIF ----------------
    float xr = 0.0f, xi = 0.0f;
    if (t < 512) {
        // Hermitian -> complex packing fused with the s=256 butterfly.
        float2 Ka = Ksh[t];
        float2 Kb = Ksh[512 - t];
        const int tb = t ^ 256;
        float2 Kc = Ksh[tb];
        float2 Kd = Ksh[512 - tb];
        float Wx = co, Wy = -si;                   // e^{+2pi i t/1024}
        float hsx = 0.5f*(Ka.x + Kb.x), hsy = 0.5f*(Ka.y - Kb.y);
        float hdx = 0.5f*(Ka.x - Kb.x), hdy = 0.5f*(Ka.y + Kb.y);
        float Yax = hsx - Wy*hdx - Wx*hdy;
        float Yay = hsy - Wy*hdy + Wx*hdx;
        // partner twiddle: e^{+2pi i (t^256)/1024} = (t<256 ? i : -i) * W
        float Wbx = (t < 256) ? -Wy :  Wy;
        float Wby = (t < 256) ?  Wx : -Wx;
        float hsx2 = 0.5f*(Kc.x + Kd.x), hsy2 = 0.5f*(Kc.y - Kd.y);
        float hdx2 = 0.5f*(Kc.x - Kd.x), hdy2 = 0.5f*(Kc.y + Kd.y);
        float Ybx = hsx2 - Wby*hdx2 - Wbx*hdy2;
        float Yby = hsy2 - Wby*hdy2 + Wbx*hdx2;
        if (t & 256) {
            float dr = Ybx - Yax, di = Yby - Yay;
            float wrev = (float)(t & 255) * (1.0f/512.0f);   // revolutions
            float ws = __builtin_amdgcn_sinf(wrev);
            float wc = __builtin_amdgcn_cosf(wrev);
            xr = dr*wc - di*ws; xi = dr*ws + di*wc;
        } else {
            xr = Yax + Ybx; xi = Yay + Yby;
        }
        Sre[t] = xr; Sim[t] = xi;
    }
    __syncthreads();

    if (t < 512) {
        // s = 128 (LDS exchange)
        float pr = Sre[t ^ 128], pi_ = Sim[t ^ 128];
        if (t & 128) {
            float dr = pr - xr, di = pi_ - xi;
            float wrev = (float)(t & 127) * (1.0f/256.0f);
            float ws = __builtin_amdgcn_sinf(wrev);
            float wc = __builtin_amdgcn_cosf(wrev);
            xr = dr*wc - di*ws; xi = dr*ws + di*wc;
        } else { xr += pr; xi += pi_; }
        Tre[t] = xr; Tim[t] = xi;
    }
    __syncthreads();

    if (t < 512) {
        // s = 64 (LDS exchange)
        float pr = Tre[t ^ 64], pi_ = Tim[t ^ 64];
        if (t & 64) {
            float dr = pr - xr, di = pi_ - xi;
            float wrev = (float)(t & 63) * (1.0f/128.0f);
            float ws = __builtin_amdgcn_sinf(wrev);
            float wc = __builtin_amdgcn_cosf(wrev);
            xr = dr*wc - di*ws; xi = dr*ws + di*wc;
        } else { xr += pr; xi += pi_; }

        // s = 32..2 (wave-internal shfl butterflies)
        #define FFT_STAGE(S_) {                                             \
            float pr2 = __shfl_xor(xr, S_), pi2 = __shfl_xor(xi, S_);       \
            if (t & S_) {                                                   \
                float dr = pr2 - xr, di = pi2 - xi;                         \
                float wrev = (float)(t & (S_-1)) * (0.5f/(float)S_);        \
                float ws = __builtin_amdgcn_sinf(wrev);                     \
                float wc = __builtin_amdgcn_cosf(wrev);                     \
                xr = dr*wc - di*ws; xi = dr*ws + di*wc;                     \
            } else { xr += pr2; xi += pi2; }                                \
        }
        FFT_STAGE(32)
        FFT_STAGE(16)
        FFT_STAGE(8)
        FFT_STAGE(4)
        FFT_STAGE(2)
        #undef FFT_STAGE
        // s = 1 (twiddle = 1)
        {
            float pr2 = __shfl_xor(xr, 1), pi2 = __shfl_xor(xi, 1);
            if (t & 1) { xr = pr2 - xr; xi = pi2 - xi; }
            else       { xr += pr2; xi += pi2; }
        }
        // thread t holds y[bitrev9(t)]; y[m] packs (x[2m], x[2m+1])
        unsigned m = __brev((unsigned)t) >> 23;
        ((float2*)out)[h*512 + m] = make_float2(xr*(1.0f/512.0f), xi*(1.0f/512.0f));
    }
}

extern "C" void kernel_launch(void* const* d_in, const int* in_sizes, int n_in,
                              void* d_out, int out_size, void* d_ws, size_t ws_size,
                              hipStream_t stream) {
    const float* log_dt     = (const float*)d_in[0];
    const float* inv_w_real = (const float*)d_in[1];
    const float* w_imag     = (const float*)d_in[2];
    const float* B_ri       = (const float*)d_in[3];
    const float* C_ri       = (const float*)d_in[4];
    const float* P_ri       = (const float*)d_in[5];
    // d_in[6] = L (constant 1024, baked in)

    ssk_nplr_kernel<<<H_DIM, 576, 0, stream>>>(log_dt, inv_w_real, w_imag,
                                               B_ri, C_ri, P_ri, (float*)d_out);
}